// Round 10
// baseline (388.844 us; speedup 1.0000x reference)
//
#include <hip/hip_runtime.h>
#include <hip/hip_cooperative_groups.h>

namespace cg = cooperative_groups;

typedef unsigned int u32;
typedef unsigned short u16;

static __device__ __forceinline__ float leaky(float v) {
    return v >= 0.0f ? v : 0.01f * v;
}

#define P1_CHUNK 8192
#define P1_T 256
#define NBK 512            // buckets = dst>>8  (requires nN <= 131072)
#define P2_T 256
#define ASPLIT 4           // fallback agg kernels
#define SBLK 1024
#define STG_CAP 14336      // LDS edge stage per bucket (mean ~12.8K, +13 sigma)
#define S1F 8388608.0f     // 2^23 fixed-point scale, layer 1
#define S2F 2097152.0f     // 2^21 fixed-point scale, layer 2

// GH(i): global exclusive-scan value without a scanC pass
static __device__ __forceinline__ int ghat(const int* __restrict__ gh,
                                           const int* __restrict__ bsum,
                                           int i, int ghN, int nE) {
    return (i == ghN) ? nE : gh[i] + bsum[i >> 10];
}

// ================= pass 1: bucket histogram (bin-major gh) =================
__global__ void k_p1hist(const int* __restrict__ dst, int* __restrict__ gh,
                         int nE, int nb) {
    __shared__ int hist[NBK];
    int t = threadIdx.x;
    hist[t] = 0; hist[t + 256] = 0;
    __syncthreads();
    int base = blockIdx.x * P1_CHUNK;
    int lim = min(P1_CHUNK, nE - base);
    if (lim == P1_CHUNK) {
        const int4* p = (const int4*)(dst + base);
        for (int i = t; i < P1_CHUNK / 4; i += P1_T) {
            int4 v = p[i];
            atomicAdd(&hist[v.x >> 8], 1);
            atomicAdd(&hist[v.y >> 8], 1);
            atomicAdd(&hist[v.z >> 8], 1);
            atomicAdd(&hist[v.w >> 8], 1);
        }
    } else {
        for (int i = t; i < lim; i += P1_T)
            atomicAdd(&hist[dst[base + i] >> 8], 1);
    }
    __syncthreads();
    gh[t * nb + blockIdx.x] = hist[t];
    gh[(t + 256) * nb + blockIdx.x] = hist[t + 256];
}

// ================= scan =================
__global__ void g_scanA(const int* __restrict__ in, int* __restrict__ out,
                        int* __restrict__ bsum, int n) {
    __shared__ int s[SBLK];
    int t = threadIdx.x, i = blockIdx.x * SBLK + t;
    int v = (i < n) ? in[i] : 0;
    s[t] = v;
    for (int o = 1; o < SBLK; o <<= 1) {
        __syncthreads();
        int x = (t >= o) ? s[t - o] : 0;
        __syncthreads();
        s[t] += x;
    }
    __syncthreads();
    if (i < n) out[i] = s[t] - v;
    if (t == SBLK - 1) bsum[blockIdx.x] = s[t];
}
__global__ void g_scanB(int* __restrict__ bsum, int nb) {
    __shared__ int s[SBLK];
    int t = threadIdx.x;
    int v = (t < nb) ? bsum[t] : 0;
    s[t] = v;
    for (int o = 1; o < SBLK; o <<= 1) {
        __syncthreads();
        int x = (t >= o) ? s[t - o] : 0;
        __syncthreads();
        s[t] += x;
    }
    __syncthreads();
    if (t < nb) bsum[t] = s[t] - v;
}

// ====== pass 1 scatter: single edge pass, counts from GH diffs =============
__global__ __launch_bounds__(256) void k_p1scatter(
        const int* __restrict__ src, const int* __restrict__ dst,
        const int* __restrict__ gh, const int* __restrict__ bsum,
        u32* __restrict__ bkt, int nE, int nb, int ghN) {
    __shared__ int cur[NBK];
    __shared__ int loff[NBK];
    __shared__ int gb[NBK];
    __shared__ int sc[NBK];
    __shared__ u32 pay[P1_CHUNK];
    __shared__ u16 bb[P1_CHUNK];
    int t = threadIdx.x;
    int blk = blockIdx.x;
    int idx0 = t * nb + blk;
    int idx1 = (t + 256) * nb + blk;
    int g0 = ghat(gh, bsum, idx0, ghN, nE);
    int c0 = ghat(gh, bsum, idx0 + 1, ghN, nE) - g0;
    int g1 = ghat(gh, bsum, idx1, ghN, nE);
    int c1 = ghat(gh, bsum, idx1 + 1, ghN, nE) - g1;
    gb[t] = g0; gb[t + 256] = g1;
    sc[t] = c0; sc[t + 256] = c1;
    for (int o = 1; o < NBK; o <<= 1) {
        __syncthreads();
        int a0 = (t >= o) ? sc[t - o] : 0;
        int a1 = (t + 256 >= o) ? sc[t + 256 - o] : 0;
        __syncthreads();
        sc[t] += a0; sc[t + 256] += a1;
    }
    __syncthreads();
    loff[t] = sc[t] - c0;           loff[t + 256] = sc[t + 256] - c1;
    cur[t] = loff[t];               cur[t + 256] = loff[t + 256];
    __syncthreads();
    int base = blk * P1_CHUNK;
    int lim = min(P1_CHUNK, nE - base);
    int n4 = lim >> 2;
    const int4* d4p = (const int4*)(dst + base);
    const int4* s4p = (const int4*)(src + base);
    for (int i = t; i < n4; i += P1_T) {
        int4 d4 = d4p[i];
        int4 s4 = s4p[i];
        int b, r;
        b = d4.x >> 8; r = atomicAdd(&cur[b], 1);
        pay[r] = (u32)(((d4.x & 255) << 17) | s4.x); bb[r] = (u16)b;
        b = d4.y >> 8; r = atomicAdd(&cur[b], 1);
        pay[r] = (u32)(((d4.y & 255) << 17) | s4.y); bb[r] = (u16)b;
        b = d4.z >> 8; r = atomicAdd(&cur[b], 1);
        pay[r] = (u32)(((d4.z & 255) << 17) | s4.z); bb[r] = (u16)b;
        b = d4.w >> 8; r = atomicAdd(&cur[b], 1);
        pay[r] = (u32)(((d4.w & 255) << 17) | s4.w); bb[r] = (u16)b;
    }
    for (int i = (n4 << 2) + t; i < lim; i += P1_T) {
        int d = dst[base + i], s = src[base + i];
        int b = d >> 8;
        int r = atomicAdd(&cur[b], 1);
        pay[r] = (u32)(((d & 255) << 17) | s);
        bb[r] = (u16)b;
    }
    __syncthreads();
    for (int i = t; i < lim; i += P1_T) {
        int b = bb[i];
        bkt[gb[b] + (i - loff[b])] = pay[i];
    }
}

// ====== mega: one cooperative kernel for cnt+agg1+fin1+agg2+fin2+mlp =======
__global__ __launch_bounds__(256, 2) void k_mega(
        const u32* __restrict__ bkt, const int* __restrict__ gh,
        const int* __restrict__ bsum,
        const int* __restrict__ x, const float* __restrict__ emb,
        const float* __restrict__ W1, const float* __restrict__ b1,
        const float* __restrict__ W2, const float* __restrict__ b2,
        const int* __restrict__ home, const int* __restrict__ away,
        const float* __restrict__ lw1, const float* __restrict__ lb1,
        const float* __restrict__ lw2, const float* __restrict__ lb2,
        const float* __restrict__ lw3, const float* __restrict__ lb3,
        float4* hd0, float4* hd2, float4* h2, float* __restrict__ out,
        int nE, int nb, int ghN, int nN, int nM) {
    cg::grid_group grid = cg::this_grid();
    __shared__ u32 stg[STG_CAP];
    __shared__ int acc[768];
    __shared__ float mw[235];
    int t = threadIdx.x, b = blockIdx.x;
    int base = ghat(gh, bsum, b * nb, ghN, nE);
    int end  = (b + 1 < NBK) ? ghat(gh, bsum, (b + 1) * nb, ghN, nE) : nE;
    int sz = end - base;
    bool fits = (sz <= STG_CAP);

    // stage edges in LDS once
    if (fits) for (int i = t; i < sz; i += 256) stg[i] = bkt[base + i];

    // ---- phase 1: degree histogram -> di, self(hd0), publish hd0 ----
    acc[t] = 0;
    __syncthreads();
    if (fits) { for (int i = t; i < sz; i += 256) atomicAdd(&acc[stg[i] >> 17], 1); }
    else      { for (int i = t; i < sz; i += 256) atomicAdd(&acc[bkt[base + i] >> 17], 1); }
    __syncthreads();
    int deg = acc[t];
    float di = rsqrtf((float)deg + 1.0f);
    int d = b * 256 + t;
    float4 self = make_float4(0.f, 0.f, 0.f, 0.f);
    if (d < nN) {
        int xi = x[d] * 3;
        self = make_float4(emb[xi] * di, emb[xi + 1] * di, emb[xi + 2] * di, 0.f);
        hd0[d] = self;
    }
    grid.sync();

    // ---- phase 2: layer-1 agg (fixed point) + inline fin1 -> hd2 ----
    acc[t] = 0; acc[t + 256] = 0; acc[t + 512] = 0;
    __syncthreads();
    if (fits) {
        for (int i = t; i < sz; i += 256) {
            u32 v = stg[i];
            float4 h = hd0[v & 0x1FFFFu];
            int bin = (int)(v >> 17) * 3;
            atomicAdd(&acc[bin + 0], __float2int_rn(h.x * S1F));
            atomicAdd(&acc[bin + 1], __float2int_rn(h.y * S1F));
            atomicAdd(&acc[bin + 2], __float2int_rn(h.z * S1F));
        }
    } else {
        for (int i = t; i < sz; i += 256) {
            u32 v = bkt[base + i];
            float4 h = hd0[v & 0x1FFFFu];
            int bin = (int)(v >> 17) * 3;
            atomicAdd(&acc[bin + 0], __float2int_rn(h.x * S1F));
            atomicAdd(&acc[bin + 1], __float2int_rn(h.y * S1F));
            atomicAdd(&acc[bin + 2], __float2int_rn(h.z * S1F));
        }
    }
    __syncthreads();
    float4 self2 = make_float4(0.f, 0.f, 0.f, 0.f);
    if (d < nN) {
        float s0 = (float)acc[t * 3 + 0] * (1.0f / S1F);
        float s1 = (float)acc[t * 3 + 1] * (1.0f / S1F);
        float s2 = (float)acc[t * 3 + 2] * (1.0f / S1F);
        float a0 = di * (s0 + self.x);
        float a1 = di * (s1 + self.y);
        float a2 = di * (s2 + self.z);
        float o0 = 0.f, o1 = 0.f, o2 = 0.f;
#pragma unroll
        for (int k = 0; k < 16; ++k) {
            float p = leaky(a0 * W1[k] + a1 * W1[16 + k] + a2 * W1[32 + k] + b1[k]);
            o0 += p * W2[k * 3 + 0];
            o1 += p * W2[k * 3 + 1];
            o2 += p * W2[k * 3 + 2];
        }
        self2 = make_float4(o0 * di, o1 * di, o2 * di, 0.f);
        hd2[d] = self2;
    }
    grid.sync();

    // ---- phase 3: layer-2 agg + inline fin2 -> h2 ----
    acc[t] = 0; acc[t + 256] = 0; acc[t + 512] = 0;
    __syncthreads();
    if (fits) {
        for (int i = t; i < sz; i += 256) {
            u32 v = stg[i];
            float4 h = hd2[v & 0x1FFFFu];
            int bin = (int)(v >> 17) * 3;
            atomicAdd(&acc[bin + 0], __float2int_rn(h.x * S2F));
            atomicAdd(&acc[bin + 1], __float2int_rn(h.y * S2F));
            atomicAdd(&acc[bin + 2], __float2int_rn(h.z * S2F));
        }
    } else {
        for (int i = t; i < sz; i += 256) {
            u32 v = bkt[base + i];
            float4 h = hd2[v & 0x1FFFFu];
            int bin = (int)(v >> 17) * 3;
            atomicAdd(&acc[bin + 0], __float2int_rn(h.x * S2F));
            atomicAdd(&acc[bin + 1], __float2int_rn(h.y * S2F));
            atomicAdd(&acc[bin + 2], __float2int_rn(h.z * S2F));
        }
    }
    __syncthreads();
    if (d < nN) {
        float s0 = (float)acc[t * 3 + 0] * (1.0f / S2F);
        float s1 = (float)acc[t * 3 + 1] * (1.0f / S2F);
        float s2 = (float)acc[t * 3 + 2] * (1.0f / S2F);
        h2[d] = make_float4(leaky(di * (s0 + self2.x) + b2[0]),
                            leaky(di * (s1 + self2.y) + b2[1]),
                            leaky(di * (s2 + self2.z) + b2[2]), 0.f);
    }
    // load MLP weights (own block copy) while waiting
    if (t < 96)       mw[t] = lw1[t];
    else if (t < 112) mw[t] = lb1[t - 96];
    else if (t < 208) mw[t] = lw2[t - 112];
    else if (t < 214) mw[t] = lb2[t - 208];
    else if (t < 232) mw[t] = lw3[t - 214];
    else if (t < 235) mw[t] = lb3[t - 232];
    grid.sync();

    // ---- phase 4: per-match MLP (grid-strided quads) ----
    const float* sw1 = mw;        const float* sb1 = mw + 96;
    const float* sw2 = mw + 112;  const float* sb2 = mw + 208;
    const float* sw3 = mw + 214;  const float* sb3 = mw + 232;
    int nQ = (nM + 3) >> 2;
    for (int qd = b * 256 + t; qd < nQ; qd += NBK * 256) {
        int m0 = qd * 4;
        int nq = min(4, nM - m0);
        int hidx[4], aidx[4];
        if (nq == 4) {
            int4 hv = *(const int4*)&home[m0];
            int4 av = *(const int4*)&away[m0];
            hidx[0] = hv.x; hidx[1] = hv.y; hidx[2] = hv.z; hidx[3] = hv.w;
            aidx[0] = av.x; aidx[1] = av.y; aidx[2] = av.z; aidx[3] = av.w;
        } else {
            for (int j = 0; j < nq; ++j) { hidx[j] = home[m0 + j]; aidx[j] = away[m0 + j]; }
        }
        float res[12];
        for (int j = 0; j < nq; ++j) {
            float4 zh = h2[hidx[j]];
            float4 za = h2[aidx[j]];
            float z[6] = {zh.x, zh.y, zh.z, za.x, za.y, za.z};
            float t1[16];
#pragma unroll
            for (int k = 0; k < 16; ++k) {
                float p = sb1[k];
#pragma unroll
                for (int q = 0; q < 6; ++q) p += z[q] * sw1[q * 16 + k];
                t1[k] = leaky(p);
            }
            float t2[6];
#pragma unroll
            for (int k = 0; k < 6; ++k) {
                float p = sb2[k];
#pragma unroll
                for (int q = 0; q < 16; ++q) p += t1[q] * sw2[q * 6 + k];
                t2[k] = leaky(p);
            }
#pragma unroll
            for (int k = 0; k < 3; ++k) {
                float p = sb3[k];
#pragma unroll
                for (int q = 0; q < 6; ++q) p += t2[q] * sw3[q * 3 + k];
                res[j * 3 + k] = leaky(p);
            }
        }
        if (nq == 4) {
            float4* o4 = (float4*)&out[m0 * 3];
            o4[0] = make_float4(res[0], res[1], res[2], res[3]);
            o4[1] = make_float4(res[4], res[5], res[6], res[7]);
            o4[2] = make_float4(res[8], res[9], res[10], res[11]);
        } else {
            for (int j = 0; j < nq * 3; ++j) out[m0 * 3 + j] = res[j];
        }
    }
}

// ================= fallback kernels (R8 path) =================
__global__ void k_cnt1(const u32* __restrict__ bkt, const int* __restrict__ gh,
                       const int* __restrict__ bsum,
                       const int* __restrict__ x, const float* __restrict__ emb,
                       float* __restrict__ dinv, float4* __restrict__ hd0,
                       int nE, int nb, int ghN, int nN) {
    __shared__ int h[256];
    int t = threadIdx.x, b = blockIdx.x;
    int base = ghat(gh, bsum, b * nb, ghN, nE);
    int end  = (b + 1 < NBK) ? ghat(gh, bsum, (b + 1) * nb, ghN, nE) : nE;
    h[t] = 0;
    __syncthreads();
    for (int i = base + t; i < end; i += P2_T)
        atomicAdd(&h[bkt[i] >> 17], 1);
    __syncthreads();
    int d = b * 256 + t;
    if (d < nN) {
        float di = rsqrtf((float)h[t] + 1.0f);
        dinv[d] = di;
        int xi = x[d] * 3;
        hd0[d] = make_float4(emb[xi] * di, emb[xi + 1] * di, emb[xi + 2] * di, 0.f);
    }
}
__global__ __launch_bounds__(256) void k_aggI(
        const u32* __restrict__ bkt, const int* __restrict__ gh,
        const int* __restrict__ bsum,
        const float4* __restrict__ tab, float* __restrict__ pacc,
        int nE, int nb, int ghN, float scale, float inv_scale) {
    __shared__ int acc[768];
    int t = threadIdx.x;
    int blk = blockIdx.x, b = blk >> 2, s = blk & 3;
    int base = ghat(gh, bsum, b * nb, ghN, nE);
    int end  = (b + 1 < NBK) ? ghat(gh, bsum, (b + 1) * nb, ghN, nE) : nE;
    int sz = end - base;
    int chunk = (sz + ASPLIT - 1) / ASPLIT;
    int st = min(base + s * chunk, end);
    int en = min(st + chunk, end);
    acc[t] = 0; acc[t + 256] = 0; acc[t + 512] = 0;
    __syncthreads();
    for (int i = st + t; i < en; i += P2_T) {
        u32 v = bkt[i];
        float4 h = tab[v & 0x1FFFFu];
        int bin = (int)(v >> 17) * 3;
        atomicAdd(&acc[bin + 0], __float2int_rn(h.x * scale));
        atomicAdd(&acc[bin + 1], __float2int_rn(h.y * scale));
        atomicAdd(&acc[bin + 2], __float2int_rn(h.z * scale));
    }
    __syncthreads();
    float* p = pacc + (size_t)blk * 768;
    p[t]       = (float)acc[t * 3 + 0] * inv_scale;
    p[t + 256] = (float)acc[t * 3 + 1] * inv_scale;
    p[t + 512] = (float)acc[t * 3 + 2] * inv_scale;
}
__global__ void k_fin1(const float* __restrict__ pacc, const float* __restrict__ dinv,
                       const float4* __restrict__ hd0,
                       const float* __restrict__ W1, const float* __restrict__ b1,
                       const float* __restrict__ W2,
                       float4* __restrict__ hd2, int nN) {
    int d = blockIdx.x * blockDim.x + threadIdx.x;
    if (d >= nN) return;
    int b = d >> 8, q = d & 255;
    float s0 = 0.f, s1 = 0.f, s2 = 0.f;
#pragma unroll
    for (int s = 0; s < ASPLIT; ++s) {
        const float* p = pacc + (size_t)(b * ASPLIT + s) * 768;
        s0 += p[q]; s1 += p[q + 256]; s2 += p[q + 512];
    }
    float di = dinv[d];
    float4 self = hd0[d];
    float a0 = di * (s0 + self.x);
    float a1 = di * (s1 + self.y);
    float a2 = di * (s2 + self.z);
    float o0 = 0.f, o1 = 0.f, o2 = 0.f;
#pragma unroll
    for (int k = 0; k < 16; ++k) {
        float p = leaky(a0 * W1[k] + a1 * W1[16 + k] + a2 * W1[32 + k] + b1[k]);
        o0 += p * W2[k * 3 + 0];
        o1 += p * W2[k * 3 + 1];
        o2 += p * W2[k * 3 + 2];
    }
    hd2[d] = make_float4(o0 * di, o1 * di, o2 * di, 0.f);
}
__global__ void k_fin2(const float* __restrict__ pacc, const float* __restrict__ dinv,
                       const float4* __restrict__ hd2, const float* __restrict__ b2,
                       float4* __restrict__ h2, int nN) {
    int d = blockIdx.x * blockDim.x + threadIdx.x;
    if (d >= nN) return;
    int b = d >> 8, q = d & 255;
    float s0 = 0.f, s1 = 0.f, s2 = 0.f;
#pragma unroll
    for (int s = 0; s < ASPLIT; ++s) {
        const float* p = pacc + (size_t)(b * ASPLIT + s) * 768;
        s0 += p[q]; s1 += p[q + 256]; s2 += p[q + 512];
    }
    float di = dinv[d];
    float4 self = hd2[d];
    h2[d] = make_float4(leaky(di * (s0 + self.x) + b2[0]),
                        leaky(di * (s1 + self.y) + b2[1]),
                        leaky(di * (s2 + self.z) + b2[2]), 0.f);
}
__global__ __launch_bounds__(256) void k_mlp4v(
        const int* __restrict__ home, const int* __restrict__ away,
        const float4* __restrict__ h2,
        const float* __restrict__ lw1, const float* __restrict__ lb1,
        const float* __restrict__ lw2, const float* __restrict__ lb2,
        const float* __restrict__ lw3, const float* __restrict__ lb3,
        float* __restrict__ out, int nM) {
    __shared__ float s[235];
    int t = threadIdx.x;
    if (t < 96)       s[t] = lw1[t];
    else if (t < 112) s[t] = lb1[t - 96];
    else if (t < 208) s[t] = lw2[t - 112];
    else if (t < 214) s[t] = lb2[t - 208];
    else if (t < 232) s[t] = lw3[t - 214];
    else if (t < 235) s[t] = lb3[t - 232];
    __syncthreads();
    const float* sw1 = s;        const float* sb1 = s + 96;
    const float* sw2 = s + 112;  const float* sb2 = s + 208;
    const float* sw3 = s + 214;  const float* sb3 = s + 232;
    int i = blockIdx.x * blockDim.x + threadIdx.x;
    int m0 = i * 4;
    if (m0 >= nM) return;
    float res[12];
    int nq = min(4, nM - m0);
    int hidx[4], aidx[4];
    if (nq == 4) {
        int4 hv = *(const int4*)&home[m0];
        int4 av = *(const int4*)&away[m0];
        hidx[0] = hv.x; hidx[1] = hv.y; hidx[2] = hv.z; hidx[3] = hv.w;
        aidx[0] = av.x; aidx[1] = av.y; aidx[2] = av.z; aidx[3] = av.w;
    } else {
        for (int j = 0; j < nq; ++j) { hidx[j] = home[m0 + j]; aidx[j] = away[m0 + j]; }
    }
    for (int j = 0; j < nq; ++j) {
        float4 zh = h2[hidx[j]];
        float4 za = h2[aidx[j]];
        float z[6] = {zh.x, zh.y, zh.z, za.x, za.y, za.z};
        float t1[16];
#pragma unroll
        for (int k = 0; k < 16; ++k) {
            float p = sb1[k];
#pragma unroll
            for (int q = 0; q < 6; ++q) p += z[q] * sw1[q * 16 + k];
            t1[k] = leaky(p);
        }
        float t2[6];
#pragma unroll
        for (int k = 0; k < 6; ++k) {
            float p = sb2[k];
#pragma unroll
            for (int q = 0; q < 16; ++q) p += t1[q] * sw2[q * 6 + k];
            t2[k] = leaky(p);
        }
#pragma unroll
        for (int k = 0; k < 3; ++k) {
            float p = sb3[k];
#pragma unroll
            for (int q = 0; q < 6; ++q) p += t2[q] * sw3[q * 3 + k];
            res[j * 3 + k] = leaky(p);
        }
    }
    if (nq == 4) {
        float4* o4 = (float4*)&out[m0 * 3];
        o4[0] = make_float4(res[0], res[1], res[2], res[3]);
        o4[1] = make_float4(res[4], res[5], res[6], res[7]);
        o4[2] = make_float4(res[8], res[9], res[10], res[11]);
    } else {
        for (int j = 0; j < nq * 3; ++j) out[m0 * 3 + j] = res[j];
    }
}

// ================= launch =================
extern "C" void kernel_launch(void* const* d_in, const int* in_sizes, int n_in,
                              void* d_out, int out_size, void* d_ws, size_t ws_size,
                              hipStream_t stream) {
    const int*   x    = (const int*)d_in[0];
    const int*   ei   = (const int*)d_in[1];
    const int*   home = (const int*)d_in[2];
    const int*   away = (const int*)d_in[3];
    const float* emb  = (const float*)d_in[4];
    const float* W1   = (const float*)d_in[5];
    const float* b1   = (const float*)d_in[6];
    const float* W2   = (const float*)d_in[7];
    const float* b2   = (const float*)d_in[8];
    const float* lw1  = (const float*)d_in[9];
    const float* lb1  = (const float*)d_in[10];
    const float* lw2  = (const float*)d_in[11];
    const float* lb2  = (const float*)d_in[12];
    const float* lw3  = (const float*)d_in[13];
    const float* lb3  = (const float*)d_in[14];
    float* out = (float*)d_out;

    int nN = in_sizes[0];       // 100000
    int nE = in_sizes[1] / 2;   // 5M
    int nM = in_sizes[2];       // 1M
    const int* src = ei;
    const int* dst = ei + nE;
    const int B = 256;

    int nb1 = (nE + P1_CHUNK - 1) / P1_CHUNK;
    int ghN = NBK * nb1;
    const int nbs = (ghN + SBLK - 1) / SBLK;
    const size_t paccN = (size_t)NBK * ASPLIT * 768;   // floats (fallback only)

    size_t need = (size_t)3 * nN * 16 + (size_t)nE * 4 + (size_t)(ghN + 1) * 4 +
                  paccN * 4 + (size_t)nN * 4 + (size_t)(nbs + 8) * 4;

    if (nN <= NBK * 256 && ws_size >= need && nbs <= SBLK) {
        char* w = (char*)d_ws;
        float4* hd0 = (float4*)w;                 w += (size_t)nN * 16;
        float4* hd2 = (float4*)w;                 w += (size_t)nN * 16;
        float4* h2  = (float4*)w;                 w += (size_t)nN * 16;
        u32* bkt  = (u32*)w;                      w += (size_t)nE * 4;
        float* pacc = (float*)w;                  w += paccN * 4;
        int* gh   = (int*)w;                      w += (size_t)(ghN + 1) * 4;
        float* dinv = (float*)w;                  w += (size_t)nN * 4;
        int* bsum = (int*)w;

        k_p1hist<<<nb1, P1_T, 0, stream>>>(dst, gh, nE, nb1);
        g_scanA<<<nbs, SBLK, 0, stream>>>(gh, gh, bsum, ghN);
        g_scanB<<<1, SBLK, 0, stream>>>(bsum, nbs);
        k_p1scatter<<<nb1, P1_T, 0, stream>>>(src, dst, gh, bsum, bkt, nE, nb1, ghN);

        void* args[] = {
            (void*)&bkt, (void*)&gh, (void*)&bsum, (void*)&x, (void*)&emb,
            (void*)&W1, (void*)&b1, (void*)&W2, (void*)&b2,
            (void*)&home, (void*)&away,
            (void*)&lw1, (void*)&lb1, (void*)&lw2, (void*)&lb2,
            (void*)&lw3, (void*)&lb3,
            (void*)&hd0, (void*)&hd2, (void*)&h2, (void*)&out,
            (void*)&nE, (void*)&nb1, (void*)&ghN, (void*)&nN, (void*)&nM
        };
        hipError_t err = hipLaunchCooperativeKernel(
            reinterpret_cast<void*>(k_mega), dim3(NBK), dim3(256), args, 0, stream);
        if (err != hipSuccess) {
            // non-cooperative fallback: R8 sequence
            k_cnt1<<<NBK, P2_T, 0, stream>>>(bkt, gh, bsum, x, emb, dinv, hd0,
                                             nE, nb1, ghN, nN);
            k_aggI<<<NBK * ASPLIT, P2_T, 0, stream>>>(bkt, gh, bsum, hd0, pacc,
                                                      nE, nb1, ghN, S1F, 1.0f / S1F);
            k_fin1<<<(nN + B - 1) / B, B, 0, stream>>>(pacc, dinv, hd0, W1, b1, W2,
                                                       hd2, nN);
            k_aggI<<<NBK * ASPLIT, P2_T, 0, stream>>>(bkt, gh, bsum, hd2, pacc,
                                                      nE, nb1, ghN, S2F, 1.0f / S2F);
            k_fin2<<<(nN + B - 1) / B, B, 0, stream>>>(pacc, dinv, hd2, b2, h2, nN);
            int nQuads = (nM + 3) / 4;
            k_mlp4v<<<(nQuads + B - 1) / B, B, 0, stream>>>(home, away, h2,
                                                            lw1, lb1, lw2, lb2,
                                                            lw3, lb3, out, nM);
        }
    } else {
        // minimal fallback (should not trigger at these sizes): R8 sequence with
        // whatever fits — reuse same layout assuming ws is large enough anyway.
        char* w = (char*)d_ws;
        float4* hd0 = (float4*)w;                 w += (size_t)nN * 16;
        float4* hd2 = (float4*)w;                 w += (size_t)nN * 16;
        float4* h2  = (float4*)w;                 w += (size_t)nN * 16;
        u32* bkt  = (u32*)w;                      w += (size_t)nE * 4;
        float* pacc = (float*)w;                  w += paccN * 4;
        int* gh   = (int*)w;                      w += (size_t)(ghN + 1) * 4;
        float* dinv = (float*)w;                  w += (size_t)nN * 4;
        int* bsum = (int*)w;

        k_p1hist<<<nb1, P1_T, 0, stream>>>(dst, gh, nE, nb1);
        g_scanA<<<nbs, SBLK, 0, stream>>>(gh, gh, bsum, ghN);
        g_scanB<<<1, SBLK, 0, stream>>>(bsum, nbs);
        k_p1scatter<<<nb1, P1_T, 0, stream>>>(src, dst, gh, bsum, bkt, nE, nb1, ghN);
        k_cnt1<<<NBK, P2_T, 0, stream>>>(bkt, gh, bsum, x, emb, dinv, hd0,
                                         nE, nb1, ghN, nN);
        k_aggI<<<NBK * ASPLIT, P2_T, 0, stream>>>(bkt, gh, bsum, hd0, pacc,
                                                  nE, nb1, ghN, S1F, 1.0f / S1F);
        k_fin1<<<(nN + B - 1) / B, B, 0, stream>>>(pacc, dinv, hd0, W1, b1, W2,
                                                   hd2, nN);
        k_aggI<<<NBK * ASPLIT, P2_T, 0, stream>>>(bkt, gh, bsum, hd2, pacc,
                                                  nE, nb1, ghN, S2F, 1.0f / S2F);
        k_fin2<<<(nN + B - 1) / B, B, 0, stream>>>(pacc, dinv, hd2, b2, h2, nN);
        int nQuads = (nM + 3) / 4;
        k_mlp4v<<<(nQuads + B - 1) / B, B, 0, stream>>>(home, away, h2,
                                                        lw1, lb1, lw2, lb2,
                                                        lw3, lb3, out, nM);
    }
}

// Round 12
// 136.223 us; speedup vs baseline: 2.8545x; 2.8545x over previous
//
#include <hip/hip_runtime.h>

typedef unsigned int u32;
typedef unsigned short u16;

static __device__ __forceinline__ float leaky(float v) {
    return v >= 0.0f ? v : 0.01f * v;
}

#define P1_CHUNK 8192
#define NBK 512            // buckets = dst>>8  (requires nN <= 131072)
#define CAPB 16384         // per-bucket capacity; TRUE mean load = nE*256/nN
                           // = 12800 (only ~391/512 buckets populated!), +31 sigma
#define ASPLIT 4
#define S1F 8388608.0f     // 2^23 fixed-point scale, layer 1
#define S2F 2097152.0f     // 2^21 fixed-point scale, layer 2

// ====== scatter with block-level reservation (no hist/scan prepass) ========
__global__ __launch_bounds__(256) void k_p1scatterA(
        const int* __restrict__ src, const int* __restrict__ dst,
        int* __restrict__ cur, u32* __restrict__ bkt, int nE) {
    __shared__ int sc[NBK];     // counts -> inclusive scan
    __shared__ int loff[NBK];   // local exclusive offset
    __shared__ int gb[NBK];     // global reserved base (absolute)
    __shared__ int lcur[NBK];   // local ranking cursor
    __shared__ u32 pay[P1_CHUNK];
    __shared__ u16 bb[P1_CHUNK];
    int t = threadIdx.x;
    sc[t] = 0; sc[t + 256] = 0;
    __syncthreads();
    int base = blockIdx.x * P1_CHUNK;
    int lim = min(P1_CHUNK, nE - base);
    if (lim == P1_CHUNK) {
        const int4* p = (const int4*)(dst + base);
        for (int i = t; i < P1_CHUNK / 4; i += 256) {
            int4 v = p[i];
            atomicAdd(&sc[v.x >> 8], 1);
            atomicAdd(&sc[v.y >> 8], 1);
            atomicAdd(&sc[v.z >> 8], 1);
            atomicAdd(&sc[v.w >> 8], 1);
        }
    } else {
        for (int i = t; i < lim; i += 256)
            atomicAdd(&sc[dst[base + i] >> 8], 1);
    }
    __syncthreads();
    int c0 = sc[t], c1 = sc[t + 256];
    // reserve global runs (one int atomic per touched bucket per block)
    gb[t]       = (t << 14)         + ((c0 > 0) ? atomicAdd(&cur[t], c0) : 0);
    gb[t + 256] = ((t + 256) << 14) + ((c1 > 0) ? atomicAdd(&cur[t + 256], c1) : 0);
    // inclusive scan of counts for local staging layout
    for (int o = 1; o < NBK; o <<= 1) {
        __syncthreads();
        int a0 = (t >= o) ? sc[t - o] : 0;
        int a1 = (t + 256 >= o) ? sc[t + 256 - o] : 0;
        __syncthreads();
        sc[t] += a0; sc[t + 256] += a1;
    }
    __syncthreads();
    loff[t] = sc[t] - c0;           loff[t + 256] = sc[t + 256] - c1;
    lcur[t] = loff[t];              lcur[t + 256] = loff[t + 256];
    __syncthreads();
    int n4 = lim >> 2;
    const int4* d4p = (const int4*)(dst + base);
    const int4* s4p = (const int4*)(src + base);
    for (int i = t; i < n4; i += 256) {
        int4 d4 = d4p[i];
        int4 s4 = s4p[i];
        int b, r;
        b = d4.x >> 8; r = atomicAdd(&lcur[b], 1);
        pay[r] = (u32)(((d4.x & 255) << 17) | s4.x); bb[r] = (u16)b;
        b = d4.y >> 8; r = atomicAdd(&lcur[b], 1);
        pay[r] = (u32)(((d4.y & 255) << 17) | s4.y); bb[r] = (u16)b;
        b = d4.z >> 8; r = atomicAdd(&lcur[b], 1);
        pay[r] = (u32)(((d4.z & 255) << 17) | s4.z); bb[r] = (u16)b;
        b = d4.w >> 8; r = atomicAdd(&lcur[b], 1);
        pay[r] = (u32)(((d4.w & 255) << 17) | s4.w); bb[r] = (u16)b;
    }
    for (int i = (n4 << 2) + t; i < lim; i += 256) {
        int d = dst[base + i], s = src[base + i];
        int b = d >> 8;
        int r = atomicAdd(&lcur[b], 1);
        pay[r] = (u32)(((d & 255) << 17) | s);
        bb[r] = (u16)b;
    }
    __syncthreads();
    for (int i = t; i < lim; i += 256) {
        int b = bb[i];
        bkt[gb[b] + (i - loff[b])] = pay[i];
    }
}

// ====== cnt: per-bucket degree histogram -> dinv + hd0 =====================
__global__ __launch_bounds__(256) void k_cnt1F(
        const u32* __restrict__ bkt, const int* __restrict__ cur,
        const int* __restrict__ x, const float* __restrict__ emb,
        float* __restrict__ dinv, float4* __restrict__ hd0, int nN) {
    __shared__ int h[256];
    int t = threadIdx.x, b = blockIdx.x;
    int base = b << 14;
    int end = base + cur[b];
    h[t] = 0;
    __syncthreads();
    int vend = base + ((end - base) & ~3);   // base is 16B-aligned
    for (int i = base + t * 4; i < vend; i += 256 * 4) {
        uint4 v = *(const uint4*)&bkt[i];
        atomicAdd(&h[v.x >> 17], 1);
        atomicAdd(&h[v.y >> 17], 1);
        atomicAdd(&h[v.z >> 17], 1);
        atomicAdd(&h[v.w >> 17], 1);
    }
    if (vend + t < end) atomicAdd(&h[bkt[vend + t] >> 17], 1);
    __syncthreads();
    int d = b * 256 + t;
    if (d < nN) {
        float di = rsqrtf((float)h[t] + 1.0f);
        dinv[d] = di;
        int xi = x[d] * 3;
        hd0[d] = make_float4(emb[xi] * di, emb[xi + 1] * di, emb[xi + 2] * di, 0.f);
    }
}

// ====== aggI: fixed-point LDS accumulation (int atomics only) ==============
__global__ __launch_bounds__(256) void k_aggIF(
        const u32* __restrict__ bkt, const int* __restrict__ cur,
        const float4* __restrict__ tab, float* __restrict__ pacc,
        float scale, float inv_scale) {
    __shared__ int acc[768];
    int t = threadIdx.x;
    int blk = blockIdx.x, b = blk >> 2, s = blk & 3;
    int base = b << 14;
    int sz = cur[b];
    int chunk = (sz + ASPLIT - 1) / ASPLIT;
    int st = min(base + s * chunk, base + sz);
    int en = min(st + chunk, base + sz);
    acc[t] = 0; acc[t + 256] = 0; acc[t + 512] = 0;
    __syncthreads();
    int a0 = min((st + 3) & ~3, en);
    if (st + t < a0) {
        u32 v = bkt[st + t];
        float4 h = tab[v & 0x1FFFFu];
        int bin = (int)(v >> 17) * 3;
        atomicAdd(&acc[bin + 0], __float2int_rn(h.x * scale));
        atomicAdd(&acc[bin + 1], __float2int_rn(h.y * scale));
        atomicAdd(&acc[bin + 2], __float2int_rn(h.z * scale));
    }
    int vend = a0 + ((en - a0) & ~3);
    for (int i = a0 + t * 4; i < vend; i += 256 * 4) {
        uint4 v = *(const uint4*)&bkt[i];
        float4 h0 = tab[v.x & 0x1FFFFu];
        float4 h1 = tab[v.y & 0x1FFFFu];
        float4 h2 = tab[v.z & 0x1FFFFu];
        float4 h3 = tab[v.w & 0x1FFFFu];
        int b0 = (int)(v.x >> 17) * 3, b1 = (int)(v.y >> 17) * 3;
        int b2 = (int)(v.z >> 17) * 3, b3 = (int)(v.w >> 17) * 3;
        atomicAdd(&acc[b0 + 0], __float2int_rn(h0.x * scale));
        atomicAdd(&acc[b0 + 1], __float2int_rn(h0.y * scale));
        atomicAdd(&acc[b0 + 2], __float2int_rn(h0.z * scale));
        atomicAdd(&acc[b1 + 0], __float2int_rn(h1.x * scale));
        atomicAdd(&acc[b1 + 1], __float2int_rn(h1.y * scale));
        atomicAdd(&acc[b1 + 2], __float2int_rn(h1.z * scale));
        atomicAdd(&acc[b2 + 0], __float2int_rn(h2.x * scale));
        atomicAdd(&acc[b2 + 1], __float2int_rn(h2.y * scale));
        atomicAdd(&acc[b2 + 2], __float2int_rn(h2.z * scale));
        atomicAdd(&acc[b3 + 0], __float2int_rn(h3.x * scale));
        atomicAdd(&acc[b3 + 1], __float2int_rn(h3.y * scale));
        atomicAdd(&acc[b3 + 2], __float2int_rn(h3.z * scale));
    }
    if (vend + t < en) {
        u32 v = bkt[vend + t];
        float4 h = tab[v & 0x1FFFFu];
        int bin = (int)(v >> 17) * 3;
        atomicAdd(&acc[bin + 0], __float2int_rn(h.x * scale));
        atomicAdd(&acc[bin + 1], __float2int_rn(h.y * scale));
        atomicAdd(&acc[bin + 2], __float2int_rn(h.z * scale));
    }
    __syncthreads();
    float* p = pacc + (size_t)blk * 768;
    p[t]       = (float)acc[t * 3 + 0] * inv_scale;
    p[t + 256] = (float)acc[t * 3 + 1] * inv_scale;
    p[t + 512] = (float)acc[t * 3 + 2] * inv_scale;
}

// ====== fin1: combine partials + self, chain @W1->leaky->@W2, *dinv ========
__global__ void k_fin1(const float* __restrict__ pacc, const float* __restrict__ dinv,
                       const float4* __restrict__ hd0,
                       const float* __restrict__ W1, const float* __restrict__ b1,
                       const float* __restrict__ W2,
                       float4* __restrict__ hd2, int nN) {
    int d = blockIdx.x * blockDim.x + threadIdx.x;
    if (d >= nN) return;
    int b = d >> 8, q = d & 255;
    float s0 = 0.f, s1 = 0.f, s2 = 0.f;
#pragma unroll
    for (int s = 0; s < ASPLIT; ++s) {
        const float* p = pacc + (size_t)(b * ASPLIT + s) * 768;
        s0 += p[q]; s1 += p[q + 256]; s2 += p[q + 512];
    }
    float di = dinv[d];
    float4 self = hd0[d];
    float a0 = di * (s0 + self.x);
    float a1 = di * (s1 + self.y);
    float a2 = di * (s2 + self.z);
    float o0 = 0.f, o1 = 0.f, o2 = 0.f;
#pragma unroll
    for (int k = 0; k < 16; ++k) {
        float p = leaky(a0 * W1[k] + a1 * W1[16 + k] + a2 * W1[32 + k] + b1[k]);
        o0 += p * W2[k * 3 + 0];
        o1 += p * W2[k * 3 + 1];
        o2 += p * W2[k * 3 + 2];
    }
    hd2[d] = make_float4(o0 * di, o1 * di, o2 * di, 0.f);
}

// ====== fin2 ===============================================================
__global__ void k_fin2(const float* __restrict__ pacc, const float* __restrict__ dinv,
                       const float4* __restrict__ hd2, const float* __restrict__ b2,
                       float4* __restrict__ h2, int nN) {
    int d = blockIdx.x * blockDim.x + threadIdx.x;
    if (d >= nN) return;
    int b = d >> 8, q = d & 255;
    float s0 = 0.f, s1 = 0.f, s2 = 0.f;
#pragma unroll
    for (int s = 0; s < ASPLIT; ++s) {
        const float* p = pacc + (size_t)(b * ASPLIT + s) * 768;
        s0 += p[q]; s1 += p[q + 256]; s2 += p[q + 512];
    }
    float di = dinv[d];
    float4 self = hd2[d];
    h2[d] = make_float4(leaky(di * (s0 + self.x) + b2[0]),
                        leaky(di * (s1 + self.y) + b2[1]),
                        leaky(di * (s2 + self.z) + b2[2]), 0.f);
}

// ================= per-match MLP: 4 matches per thread =====================
__global__ __launch_bounds__(256) void k_mlp4v(
        const int* __restrict__ home, const int* __restrict__ away,
        const float4* __restrict__ h2,
        const float* __restrict__ lw1, const float* __restrict__ lb1,
        const float* __restrict__ lw2, const float* __restrict__ lb2,
        const float* __restrict__ lw3, const float* __restrict__ lb3,
        float* __restrict__ out, int nM) {
    __shared__ float s[235];
    int t = threadIdx.x;
    if (t < 96)       s[t] = lw1[t];
    else if (t < 112) s[t] = lb1[t - 96];
    else if (t < 208) s[t] = lw2[t - 112];
    else if (t < 214) s[t] = lb2[t - 208];
    else if (t < 232) s[t] = lw3[t - 214];
    else if (t < 235) s[t] = lb3[t - 232];
    __syncthreads();
    const float* sw1 = s;        const float* sb1 = s + 96;
    const float* sw2 = s + 112;  const float* sb2 = s + 208;
    const float* sw3 = s + 214;  const float* sb3 = s + 232;
    int i = blockIdx.x * blockDim.x + threadIdx.x;
    int m0 = i * 4;
    if (m0 >= nM) return;
    float res[12];
    int nq = min(4, nM - m0);
    int hidx[4], aidx[4];
    if (nq == 4) {
        int4 hv = *(const int4*)&home[m0];
        int4 av = *(const int4*)&away[m0];
        hidx[0] = hv.x; hidx[1] = hv.y; hidx[2] = hv.z; hidx[3] = hv.w;
        aidx[0] = av.x; aidx[1] = av.y; aidx[2] = av.z; aidx[3] = av.w;
    } else {
        for (int j = 0; j < nq; ++j) { hidx[j] = home[m0 + j]; aidx[j] = away[m0 + j]; }
    }
    for (int j = 0; j < nq; ++j) {
        float4 zh = h2[hidx[j]];
        float4 za = h2[aidx[j]];
        float z[6] = {zh.x, zh.y, zh.z, za.x, za.y, za.z};
        float t1[16];
#pragma unroll
        for (int k = 0; k < 16; ++k) {
            float p = sb1[k];
#pragma unroll
            for (int q = 0; q < 6; ++q) p += z[q] * sw1[q * 16 + k];
            t1[k] = leaky(p);
        }
        float t2[6];
#pragma unroll
        for (int k = 0; k < 6; ++k) {
            float p = sb2[k];
#pragma unroll
            for (int q = 0; q < 16; ++q) p += t1[q] * sw2[q * 6 + k];
            t2[k] = leaky(p);
        }
#pragma unroll
        for (int k = 0; k < 3; ++k) {
            float p = sb3[k];
#pragma unroll
            for (int q = 0; q < 6; ++q) p += t2[q] * sw3[q * 3 + k];
            res[j * 3 + k] = leaky(p);
        }
    }
    if (nq == 4) {
        float4* o4 = (float4*)&out[m0 * 3];
        o4[0] = make_float4(res[0], res[1], res[2], res[3]);
        o4[1] = make_float4(res[4], res[5], res[6], res[7]);
        o4[2] = make_float4(res[8], res[9], res[10], res[11]);
    } else {
        for (int j = 0; j < nq * 3; ++j) out[m0 * 3 + j] = res[j];
    }
}

// ================= tiny fallback (float-atomic push) =======================
__global__ void f_deg(const int* __restrict__ dst, float* __restrict__ deg, int nE) {
    int e = blockIdx.x * blockDim.x + threadIdx.x;
    if (e < nE) atomicAdd(&deg[dst[e]], 1.0f);
}
__global__ void f_hd0(const int* __restrict__ x, const float* __restrict__ emb,
                      float* __restrict__ dinv, float4* __restrict__ hd0, int nN) {
    int i = blockIdx.x * blockDim.x + threadIdx.x;
    if (i >= nN) return;
    float di = rsqrtf(dinv[i] + 1.0f);
    dinv[i] = di;
    int xi = x[i] * 3;
    hd0[i] = make_float4(emb[xi] * di, emb[xi + 1] * di, emb[xi + 2] * di, 0.f);
}
__global__ void f_scatter(const int* __restrict__ src, const int* __restrict__ dst,
                          const float4* __restrict__ tab, float* __restrict__ agg, int nE) {
    int e = blockIdx.x * blockDim.x + threadIdx.x;
    if (e >= nE) return;
    int s = src[e], d = dst[e];
    float4 v = tab[s];
    atomicAdd(&agg[d * 3 + 0], v.x);
    atomicAdd(&agg[d * 3 + 1], v.y);
    atomicAdd(&agg[d * 3 + 2], v.z);
}
__global__ void f_fin1(const float* __restrict__ agg, const float* __restrict__ dinv,
                       const float4* __restrict__ hd0,
                       const float* __restrict__ W1, const float* __restrict__ b1,
                       const float* __restrict__ W2, float4* __restrict__ hd2, int nN) {
    int d = blockIdx.x * blockDim.x + threadIdx.x;
    if (d >= nN) return;
    float di = dinv[d];
    float4 self = hd0[d];
    float a0 = di * (agg[d * 3 + 0] + self.x);
    float a1 = di * (agg[d * 3 + 1] + self.y);
    float a2 = di * (agg[d * 3 + 2] + self.z);
    float o0 = 0.f, o1 = 0.f, o2 = 0.f;
#pragma unroll
    for (int k = 0; k < 16; ++k) {
        float p = leaky(a0 * W1[k] + a1 * W1[16 + k] + a2 * W1[32 + k] + b1[k]);
        o0 += p * W2[k * 3 + 0];
        o1 += p * W2[k * 3 + 1];
        o2 += p * W2[k * 3 + 2];
    }
    hd2[d] = make_float4(o0 * di, o1 * di, o2 * di, 0.f);
}
__global__ void f_fin2(const float* __restrict__ agg, const float* __restrict__ dinv,
                       const float4* __restrict__ hd2, const float* __restrict__ b2,
                       float4* __restrict__ h2, int nN) {
    int d = blockIdx.x * blockDim.x + threadIdx.x;
    if (d >= nN) return;
    float di = dinv[d];
    float4 self = hd2[d];
    h2[d] = make_float4(leaky(di * (agg[d * 3 + 0] + self.x) + b2[0]),
                        leaky(di * (agg[d * 3 + 1] + self.y) + b2[1]),
                        leaky(di * (agg[d * 3 + 2] + self.z) + b2[2]), 0.f);
}

// ================= launch =================
extern "C" void kernel_launch(void* const* d_in, const int* in_sizes, int n_in,
                              void* d_out, int out_size, void* d_ws, size_t ws_size,
                              hipStream_t stream) {
    const int*   x    = (const int*)d_in[0];
    const int*   ei   = (const int*)d_in[1];
    const int*   home = (const int*)d_in[2];
    const int*   away = (const int*)d_in[3];
    const float* emb  = (const float*)d_in[4];
    const float* W1   = (const float*)d_in[5];
    const float* b1   = (const float*)d_in[6];
    const float* W2   = (const float*)d_in[7];
    const float* b2   = (const float*)d_in[8];
    const float* lw1  = (const float*)d_in[9];
    const float* lb1  = (const float*)d_in[10];
    const float* lw2  = (const float*)d_in[11];
    const float* lb2  = (const float*)d_in[12];
    const float* lw3  = (const float*)d_in[13];
    const float* lb3  = (const float*)d_in[14];
    float* out = (float*)d_out;

    const int nN = in_sizes[0];       // 100000
    const int nE = in_sizes[1] / 2;   // 5M
    const int nM = in_sizes[2];       // 1M
    const int* src = ei;
    const int* dst = ei + nE;
    const int B = 256;

    const int nb1 = (nE + P1_CHUNK - 1) / P1_CHUNK;
    const size_t paccN = (size_t)NBK * ASPLIT * 768;        // floats
    const size_t bktN = (size_t)NBK * CAPB;                 // u32 (33.5 MB)

    size_t need = (size_t)3 * nN * 16 + bktN * 4 + paccN * 4 +
                  (size_t)nN * 4 + NBK * 4;

    // capacity check with CORRECT per-bucket mean: edges hit nodes uniformly,
    // a full bucket covers 256 of nN nodes -> mean_b = nE*256/nN
    double mean_b = (double)nE * 256.0 / (double)nN;
    double sig_b = sqrt(mean_b);
    bool cap_ok = (mean_b + 10.0 * sig_b) < (double)CAPB;

    if (nN <= NBK * 256 && ws_size >= need && cap_ok) {
        char* w = (char*)d_ws;
        float4* hd0 = (float4*)w;                 w += (size_t)nN * 16;
        float4* hd2 = (float4*)w;                 w += (size_t)nN * 16;
        float4* h2  = (float4*)w;                 w += (size_t)nN * 16;
        u32* bkt  = (u32*)w;                      w += bktN * 4;
        float* pacc = (float*)w;                  w += paccN * 4;
        float* dinv = (float*)w;                  w += (size_t)nN * 4;
        int* cur  = (int*)w;

        hipMemsetAsync(cur, 0, NBK * sizeof(int), stream);
        k_p1scatterA<<<nb1, 256, 0, stream>>>(src, dst, cur, bkt, nE);
        k_cnt1F<<<NBK, 256, 0, stream>>>(bkt, cur, x, emb, dinv, hd0, nN);
        k_aggIF<<<NBK * ASPLIT, 256, 0, stream>>>(bkt, cur, hd0, pacc,
                                                  S1F, 1.0f / S1F);
        k_fin1<<<(nN + B - 1) / B, B, 0, stream>>>(pacc, dinv, hd0, W1, b1, W2,
                                                   hd2, nN);
        k_aggIF<<<NBK * ASPLIT, 256, 0, stream>>>(bkt, cur, hd2, pacc,
                                                  S2F, 1.0f / S2F);
        k_fin2<<<(nN + B - 1) / B, B, 0, stream>>>(pacc, dinv, hd2, b2, h2, nN);
        int nQuads = (nM + 3) / 4;
        k_mlp4v<<<(nQuads + B - 1) / B, B, 0, stream>>>(home, away, h2,
                                                        lw1, lb1, lw2, lb2,
                                                        lw3, lb3, out, nM);
    } else {
        // compact float-atomic fallback (correct, slower)
        char* w = (char*)d_ws;
        float4* hd0 = (float4*)w;                 w += (size_t)nN * 16;
        float4* hd2 = (float4*)w;                 w += (size_t)nN * 16;
        float4* h2  = (float4*)w;                 w += (size_t)nN * 16;
        float* agg  = (float*)w;                  w += (size_t)3 * nN * 4;
        float* dinv = (float*)w;

        hipMemsetAsync(dinv, 0, (size_t)nN * sizeof(float), stream);
        hipMemsetAsync(agg, 0, (size_t)3 * nN * sizeof(float), stream);
        f_deg<<<(nE + B - 1) / B, B, 0, stream>>>(dst, dinv, nE);
        f_hd0<<<(nN + B - 1) / B, B, 0, stream>>>(x, emb, dinv, hd0, nN);
        f_scatter<<<(nE + B - 1) / B, B, 0, stream>>>(src, dst, hd0, agg, nE);
        f_fin1<<<(nN + B - 1) / B, B, 0, stream>>>(agg, dinv, hd0, W1, b1, W2, hd2, nN);
        hipMemsetAsync(agg, 0, (size_t)3 * nN * sizeof(float), stream);
        f_scatter<<<(nE + B - 1) / B, B, 0, stream>>>(src, dst, hd2, agg, nE);
        f_fin2<<<(nN + B - 1) / B, B, 0, stream>>>(agg, dinv, hd2, b2, h2, nN);
        int nQuads = (nM + 3) / 4;
        k_mlp4v<<<(nQuads + B - 1) / B, B, 0, stream>>>(home, away, h2,
                                                        lw1, lb1, lw2, lb2,
                                                        lw3, lb3, out, nM);
    }
}